// Round 1
// 1040.500 us; speedup vs baseline: 1.0100x; 1.0100x over previous
//
#include <hip/hip_runtime.h>
#include <stdint.h>

typedef unsigned short u16;
typedef __bf16 bf16x8 __attribute__((ext_vector_type(8)));
typedef float f32x4 __attribute__((ext_vector_type(4)));
typedef unsigned short u16x8 __attribute__((ext_vector_type(8)));

#define S_DIM 4096
#define D_DIM 512
#define B_DIM 4
#define L_DIM 8921
#define LPAD  8960   // L padded to multiple of 128
#define M1    16384  // B*S

__device__ __forceinline__ u16 f2bf(float f) {
  uint32_t u = __float_as_uint(f);
  u += 0x7FFFu + ((u >> 16) & 1u);   // RNE
  return (u16)(u >> 16);
}
__device__ __forceinline__ float bf2f(u16 u) {
  return __uint_as_float(((uint32_t)u) << 16);
}
__device__ __forceinline__ void async16(const u16* g, u16* l) {
  __builtin_amdgcn_global_load_lds((const __attribute__((address_space(1))) void*)g,
                                   (__attribute__((address_space(3))) void*)l, 16, 0, 0);
}

// ---------------- cast f32 -> bf16 with optional zero tail padding ----------
__global__ __launch_bounds__(256) void cast_pad_kernel(const float* __restrict__ src,
                                                       u16* __restrict__ dst,
                                                       long long nsrc, long long ndst) {
  long long i = ((long long)blockIdx.x * 256 + threadIdx.x) * 4;
  if (i >= ndst) return;
  ushort4 o;
  if (i < nsrc) {
    float4 v = *(const float4*)(src + i);
    o.x = f2bf(v.x); o.y = f2bf(v.y); o.z = f2bf(v.z); o.w = f2bf(v.w);
  } else {
    o.x = 0; o.y = 0; o.z = 0; o.w = 0;
  }
  *(ushort4*)(dst + i) = o;
}

// ---------------- shared 128x128xK NT GEMM core (m97 structure) -------------
// C[tileM+128][tileN+128] += A[M,K] * B[N,K]^T, K=512, bf16, f32 acc.
__device__ __forceinline__ void gemm_core(const u16* __restrict__ A, const u16* __restrict__ B,
                                          int tileM, int tileN, u16* Al, u16* Bl,
                                          f32x4 acc[4][4], int waveM, int waveN,
                                          int quad, int l16) {
  const int t = threadIdx.x;
  const int r0 = t >> 2, c0 = (t & 3) * 8;
  for (int k0 = 0; k0 < D_DIM; k0 += 32) {
    // stage 128x32 bf16 tiles of A and B: 512 16B chunks each, 2 per thread
    async16(A + (size_t)(tileM + r0) * D_DIM + k0 + c0,        Al + t * 8);
    async16(A + (size_t)(tileM + r0 + 64) * D_DIM + k0 + c0,   Al + (t + 256) * 8);
    async16(B + (size_t)(tileN + r0) * D_DIM + k0 + c0,        Bl + t * 8);
    async16(B + (size_t)(tileN + r0 + 64) * D_DIM + k0 + c0,   Bl + (t + 256) * 8);
    __syncthreads();   // drains vmcnt for global_load_lds
    bf16x8 af[4], bfr[4];
#pragma unroll
    for (int mi = 0; mi < 4; ++mi)
      af[mi] = *(const bf16x8*)&Al[(waveM + mi * 16 + l16) * 32 + quad * 8];
#pragma unroll
    for (int ni = 0; ni < 4; ++ni)
      bfr[ni] = *(const bf16x8*)&Bl[(waveN + ni * 16 + l16) * 32 + quad * 8];
#pragma unroll
    for (int mi = 0; mi < 4; ++mi)
#pragma unroll
      for (int ni = 0; ni < 4; ++ni)
        acc[mi][ni] = __builtin_amdgcn_mfma_f32_16x16x32_bf16(af[mi], bfr[ni], acc[mi][ni], 0, 0, 0);
    __syncthreads();   // before next-iter LDS overwrite
  }
}

// ---------------- GEMM1: weights = tanh(x @ W1^T), bf16 out -----------------
__global__ __launch_bounds__(256) void gemm1_tanh(const u16* __restrict__ A,  // x_bf [16384,512]
                                                  const u16* __restrict__ B,  // W1_bf [512,512]
                                                  u16* __restrict__ C) {      // weights [16384,512]
  __shared__ __align__(16) u16 Al[128 * 32];
  __shared__ __align__(16) u16 Bl[128 * 32];
  const int t = threadIdx.x, lane = t & 63, wave = t >> 6;
  const int quad = lane >> 4, l16 = lane & 15;
  const int tileM = blockIdx.y * 128, tileN = blockIdx.x * 128;
  const int waveM = (wave >> 1) * 64, waveN = (wave & 1) * 64;
  f32x4 acc[4][4];
  const f32x4 z = {0.f, 0.f, 0.f, 0.f};
#pragma unroll
  for (int mi = 0; mi < 4; ++mi)
#pragma unroll
    for (int ni = 0; ni < 4; ++ni) acc[mi][ni] = z;
  gemm_core(A, B, tileM, tileN, Al, Bl, acc, waveM, waveN, quad, l16);
#pragma unroll
  for (int mi = 0; mi < 4; ++mi) {
    const int m0 = tileM + waveM + mi * 16 + quad * 4;
#pragma unroll
    for (int ni = 0; ni < 4; ++ni) {
      const int n = tileN + waveN + ni * 16 + l16;
#pragma unroll
      for (int r = 0; r < 4; ++r)
        C[(size_t)(m0 + r) * D_DIM + n] = f2bf(tanhf(acc[mi][ni][r]));
    }
  }
}

// ---------------- GEMM2 (chunked): exp(W2 @ weights_b^T) + rowsum -----------
// Processes L-rows [l_base, l_base + lc_rows); scores is a [B][lc_rows][S]
// bf16 chunk buffer. rowsum indexed by absolute l.
__global__ __launch_bounds__(256) void gemm2_exp_chunk(const u16* __restrict__ A,    // W2_bf [8960,512]
                                                       const u16* __restrict__ Ball, // weights [16384,512]
                                                       u16* __restrict__ scores,     // [4,lc_rows,4096] bf16
                                                       float* __restrict__ rowsum,   // [4,8960]
                                                       int l_base, int lc_rows) {
  __shared__ __align__(16) u16 Al[128 * 32];
  __shared__ __align__(16) u16 Bl[128 * 32];
  const int b = blockIdx.z;
  const u16* B = Ball + (size_t)b * S_DIM * D_DIM;
  const int t = threadIdx.x, lane = t & 63, wave = t >> 6;
  const int quad = lane >> 4, l16 = lane & 15;
  const int tileM = l_base + blockIdx.y * 128, tileN = blockIdx.x * 128;
  const int waveM = (wave >> 1) * 64, waveN = (wave & 1) * 64;
  f32x4 acc[4][4];
  const f32x4 z = {0.f, 0.f, 0.f, 0.f};
#pragma unroll
  for (int mi = 0; mi < 4; ++mi)
#pragma unroll
    for (int ni = 0; ni < 4; ++ni) acc[mi][ni] = z;
  gemm_core(A, B, tileM, tileN, Al, Bl, acc, waveM, waveN, quad, l16);

#pragma unroll
  for (int mi = 0; mi < 4; ++mi) {
    const int l0 = tileM + waveM + mi * 16 + quad * 4;   // absolute l
    float rs[4] = {0.f, 0.f, 0.f, 0.f};
#pragma unroll
    for (int ni = 0; ni < 4; ++ni) {
      const int s = tileN + waveN + ni * 16 + l16;
#pragma unroll
      for (int r = 0; r < 4; ++r) {
        const float ev = __expf(acc[mi][ni][r]);
        rs[r] += ev;
        const int l = l0 + r;
        if (l < L_DIM) {
          const size_t off = ((size_t)b * lc_rows + (l - l_base)) * S_DIM + s;
          scores[off] = f2bf(ev);
        }
      }
    }
#pragma unroll
    for (int r = 0; r < 4; ++r) {   // reduce over the 16 columns held by this quad-group
      float v = rs[r];
      v += __shfl_xor(v, 1);
      v += __shfl_xor(v, 2);
      v += __shfl_xor(v, 4);
      v += __shfl_xor(v, 8);
      if (l16 == 0) atomicAdd(&rowsum[(size_t)b * LPAD + l0 + r], v);
    }
  }
}

// ---------------- normalize + colsum (chunked, 16B loads) -------------------
// 512 threads, 64 L-rows per block, each thread owns 8 consecutive s.
__global__ __launch_bounds__(512) void normalize_colsum2(const u16* __restrict__ scores,
                                                         const float* __restrict__ rowsum,
                                                         float* __restrict__ att,
                                                         float* __restrict__ colsum,
                                                         int l_base, int lc_rows) {
  const int b = blockIdx.y;
  const int l0 = blockIdx.x * 64;          // chunk-relative
  const int t = threadIdx.x;
  const int s = t * 8;
  __shared__ float sc[64];
  if (t < 64) {
    const int l = l_base + l0 + t;
    sc[t] = (l < L_DIM) ? 1.0f / rowsum[(size_t)b * LPAD + l] : 0.0f;
  }
  __syncthreads();
  float c0 = 0.f, c1 = 0.f, c2 = 0.f, c3 = 0.f, c4 = 0.f, c5 = 0.f, c6 = 0.f, c7 = 0.f;
  int rmax = L_DIM - (l_base + l0);
  if (rmax > 64) rmax = 64;
  for (int i = 0; i < rmax; ++i) {
    const size_t soff = ((size_t)b * lc_rows + l0 + i) * S_DIM + s;
    u16x8 u = *(const u16x8*)(scores + soff);
    const float sl = sc[i];
    const float v0 = bf2f((u16)u[0]) * sl, v1 = bf2f((u16)u[1]) * sl;
    const float v2 = bf2f((u16)u[2]) * sl, v3 = bf2f((u16)u[3]) * sl;
    const float v4 = bf2f((u16)u[4]) * sl, v5 = bf2f((u16)u[5]) * sl;
    const float v6 = bf2f((u16)u[6]) * sl, v7 = bf2f((u16)u[7]) * sl;
    const size_t aoff = ((size_t)b * L_DIM + (l_base + l0 + i)) * S_DIM + s;
    float4 w0 = {v0, v1, v2, v3}, w1 = {v4, v5, v6, v7};
    *(float4*)(att + aoff)     = w0;
    *(float4*)(att + aoff + 4) = w1;
    c0 += v0; c1 += v1; c2 += v2; c3 += v3;
    c4 += v4; c5 += v5; c6 += v6; c7 += v7;
  }
  float* cs = colsum + (size_t)b * S_DIM + s;
  atomicAdd(cs + 0, c0); atomicAdd(cs + 1, c1);
  atomicAdd(cs + 2, c2); atomicAdd(cs + 3, c3);
  atomicAdd(cs + 4, c4); atomicAdd(cs + 5, c5);
  atomicAdd(cs + 6, c6); atomicAdd(cs + 7, c7);
}

// ---------------- legacy f32 fallback (only if ws < ~48MB) ------------------
template <bool BF16WS>
__global__ __launch_bounds__(256) void gemm2_exp(const u16* __restrict__ A,
                                                 const u16* __restrict__ Ball,
                                                 u16* __restrict__ scores,
                                                 float* __restrict__ attout,
                                                 float* __restrict__ rowsum) {
  __shared__ __align__(16) u16 Al[128 * 32];
  __shared__ __align__(16) u16 Bl[128 * 32];
  const int b = blockIdx.z;
  const u16* B = Ball + (size_t)b * S_DIM * D_DIM;
  const int t = threadIdx.x, lane = t & 63, wave = t >> 6;
  const int quad = lane >> 4, l16 = lane & 15;
  const int tileM = blockIdx.y * 128, tileN = blockIdx.x * 128;
  const int waveM = (wave >> 1) * 64, waveN = (wave & 1) * 64;
  f32x4 acc[4][4];
  const f32x4 z = {0.f, 0.f, 0.f, 0.f};
#pragma unroll
  for (int mi = 0; mi < 4; ++mi)
#pragma unroll
    for (int ni = 0; ni < 4; ++ni) acc[mi][ni] = z;
  gemm_core(A, B, tileM, tileN, Al, Bl, acc, waveM, waveN, quad, l16);
#pragma unroll
  for (int mi = 0; mi < 4; ++mi) {
    const int l0 = tileM + waveM + mi * 16 + quad * 4;
    float rs[4] = {0.f, 0.f, 0.f, 0.f};
#pragma unroll
    for (int ni = 0; ni < 4; ++ni) {
      const int s = tileN + waveN + ni * 16 + l16;
#pragma unroll
      for (int r = 0; r < 4; ++r) {
        const float ev = __expf(acc[mi][ni][r]);
        rs[r] += ev;
        const int l = l0 + r;
        if (l < L_DIM) {
          const size_t off = ((size_t)b * L_DIM + l) * S_DIM + s;
          if (BF16WS) scores[off] = f2bf(ev);
          else        attout[off] = ev;
        }
      }
    }
#pragma unroll
    for (int r = 0; r < 4; ++r) {
      float v = rs[r];
      v += __shfl_xor(v, 1);
      v += __shfl_xor(v, 2);
      v += __shfl_xor(v, 4);
      v += __shfl_xor(v, 8);
      if (l16 == 0) atomicAdd(&rowsum[(size_t)b * LPAD + l0 + r], v);
    }
  }
}

template <bool BF16WS>
__global__ __launch_bounds__(256) void normalize_colsum(const u16* __restrict__ scores,
                                                        const float* __restrict__ rowsum,
                                                        float* __restrict__ att,
                                                        float* __restrict__ colsum) {
  const int b = blockIdx.y;
  const int l0 = blockIdx.x * 32;
  const int t = threadIdx.x;
  __shared__ float sc[32];
  if (t < 32) {
    const int l = l0 + t;
    sc[t] = (l < L_DIM) ? 1.0f / rowsum[(size_t)b * LPAD + l] : 0.0f;
  }
  __syncthreads();
#pragma unroll
  for (int p = 0; p < 4; ++p) {
    const int s = p * 1024 + t * 4;
    float c0 = 0.f, c1 = 0.f, c2 = 0.f, c3 = 0.f;
    for (int i = 0; i < 32; ++i) {
      const int l = l0 + i;
      if (l >= L_DIM) break;
      const size_t off = ((size_t)b * L_DIM + l) * S_DIM + s;
      const float scale = sc[i];
      float v0, v1, v2, v3;
      if (BF16WS) {
        ushort4 u = *(const ushort4*)(scores + off);
        v0 = bf2f(u.x) * scale; v1 = bf2f(u.y) * scale;
        v2 = bf2f(u.z) * scale; v3 = bf2f(u.w) * scale;
      } else {
        float4 u = *(const float4*)(att + off);
        v0 = u.x * scale; v1 = u.y * scale; v2 = u.z * scale; v3 = u.w * scale;
      }
      float4 o = {v0, v1, v2, v3};
      *(float4*)(att + off) = o;
      c0 += v0; c1 += v1; c2 += v2; c3 += v3;
    }
    float* cs = colsum + (size_t)b * S_DIM + s;
    atomicAdd(cs + 0, c0); atomicAdd(cs + 1, c1);
    atomicAdd(cs + 2, c2); atomicAdd(cs + 3, c3);
  }
}

// ---------------- out[b,d] = sum_s colsum[b,s]*x[b,s,d] / R -----------------
__global__ __launch_bounds__(256) void out_kernel(const float* __restrict__ x,
                                                  const float* __restrict__ colsum,
                                                  float* __restrict__ out) {
  const int b = blockIdx.y, s0 = blockIdx.x * 64, t = threadIdx.x;
  float a0 = 0.f, a1 = 0.f;
  for (int i = 0; i < 64; ++i) {
    const int s = s0 + i;
    const float c = colsum[(size_t)b * S_DIM + s];
    const float* xr = x + ((size_t)b * S_DIM + s) * D_DIM;
    a0 += c * xr[t];
    a1 += c * xr[t + 256];
  }
  const float invR = 1.0f / 8921.0f;
  atomicAdd(out + b * D_DIM + t,       a0 * invR);
  atomicAdd(out + b * D_DIM + t + 256, a1 * invR);
}

extern "C" void kernel_launch(void* const* d_in, const int* in_sizes, int n_in,
                              void* d_out, int out_size, void* d_ws, size_t ws_size,
                              hipStream_t stream) {
  const float* x  = (const float*)d_in[0];   // [4,4096,512]
  const float* W1 = (const float*)d_in[1];   // [512,512]
  const float* W2 = (const float*)d_in[2];   // [8921,512]
  float* out = (float*)d_out;                // 2048 + 4*8921*4096
  float* att = out + 2048;

  char* ws = (char*)d_ws;
  u16*   x_bf   = (u16*)(ws + 0);            // 16,777,216 B
  u16*   wt_bf  = (u16*)(ws + 16777216);     // 16,777,216 B
  u16*   w1_bf  = (u16*)(ws + 33554432);     //    524,288 B
  u16*   w2_bf  = (u16*)(ws + 34078720);     //  9,175,040 B
  float* rowsum = (float*)(ws + 43253760);   //    143,360 B
  float* colsum = (float*)(ws + 43397120);   //     65,536 B
  u16*   scores = (u16*)(ws + 43462656);     // chunk buffer (sized below)

  // rowsum and colsum are adjacent: one memset covers both
  hipMemsetAsync(rowsum, 0, (size_t)B_DIM * LPAD * 4 + (size_t)B_DIM * S_DIM * 4, stream);
  hipMemsetAsync(out, 0, 2048 * sizeof(float), stream);

  cast_pad_kernel<<<8192, 256, 0, stream>>>(x,  x_bf,  8388608LL, 8388608LL);
  cast_pad_kernel<<<256,  256, 0, stream>>>(W1, w1_bf, 262144LL,  262144LL);
  cast_pad_kernel<<<4480, 256, 0, stream>>>(W2, w2_bf, (long long)L_DIM * 512, (long long)LPAD * 512);

  gemm1_tanh<<<dim3(4, 128), 256, 0, stream>>>(x_bf, w1_bf, wt_bf);

  // ---- chunked bf16-scores path: works for any ws >= ~48 MB ----
  const size_t base = 43462656ull;
  long long rows_fit = 0;
  if (ws_size > base)
    rows_fit = (long long)((ws_size - base) / ((size_t)B_DIM * S_DIM * 2));
  rows_fit = (rows_fit / 128) * 128;

  if (rows_fit >= 128) {
    const int Lc = (int)(rows_fit < LPAD ? rows_fit : LPAD);
    for (int lb = 0; lb < LPAD; lb += Lc) {
      int rows = LPAD - lb;
      if (rows > Lc) rows = Lc;
      gemm2_exp_chunk<<<dim3(S_DIM / 128, rows / 128, B_DIM), 256, 0, stream>>>(
          w2_bf, wt_bf, scores, rowsum, lb, rows);
      normalize_colsum2<<<dim3(rows / 64, B_DIM), 512, 0, stream>>>(
          scores, rowsum, att, colsum, lb, rows);
    }
  } else {
    // last-resort f32 path (ws too small for even one 128-row chunk)
    dim3 g2(S_DIM / 128, LPAD / 128, B_DIM);
    gemm2_exp<false><<<g2, 256, 0, stream>>>(w2_bf, wt_bf, (u16*)nullptr, att, rowsum);
    normalize_colsum<false><<<dim3(279, 4), 256, 0, stream>>>((const u16*)nullptr, rowsum, att, colsum);
  }

  out_kernel<<<dim3(64, 4), 256, 0, stream>>>(x, colsum, out);
}

// Round 2
// 991.572 us; speedup vs baseline: 1.0598x; 1.0493x over previous
//
#include <hip/hip_runtime.h>
#include <stdint.h>

typedef unsigned short u16;
typedef __bf16 bf16x8 __attribute__((ext_vector_type(8)));
typedef float f32x4 __attribute__((ext_vector_type(4)));

#define S_DIM 4096
#define D_DIM 512
#define B_DIM 4
#define L_DIM 8921
#define LPAD  8960   // L padded to multiple of 128
#define M1    16384  // B*S

__device__ __forceinline__ u16 f2bf(float f) {
  uint32_t u = __float_as_uint(f);
  u += 0x7FFFu + ((u >> 16) & 1u);   // RNE
  return (u16)(u >> 16);
}
__device__ __forceinline__ void async16(const u16* g, u16* l) {
  __builtin_amdgcn_global_load_lds((const __attribute__((address_space(1))) void*)g,
                                   (__attribute__((address_space(3))) void*)l, 16, 0, 0);
}

// ---------------- cast f32 -> bf16 with optional zero tail padding ----------
__global__ __launch_bounds__(256) void cast_pad_kernel(const float* __restrict__ src,
                                                       u16* __restrict__ dst,
                                                       long long nsrc, long long ndst) {
  long long i = ((long long)blockIdx.x * 256 + threadIdx.x) * 4;
  if (i >= ndst) return;
  ushort4 o;
  if (i < nsrc) {
    float4 v = *(const float4*)(src + i);
    o.x = f2bf(v.x); o.y = f2bf(v.y); o.z = f2bf(v.z); o.w = f2bf(v.w);
  } else {
    o.x = 0; o.y = 0; o.z = 0; o.w = 0;
  }
  *(ushort4*)(dst + i) = o;
}

// ---------------- shared 128x128xK NT GEMM core (m97 structure) -------------
// C[tileM+128][tileN+128] += A[M,K] * B[N,K]^T, K=512, bf16, f32 acc.
__device__ __forceinline__ void gemm_core(const u16* __restrict__ A, const u16* __restrict__ B,
                                          int tileM, int tileN, u16* Al, u16* Bl,
                                          f32x4 acc[4][4], int waveM, int waveN,
                                          int quad, int l16) {
  const int t = threadIdx.x;
  const int r0 = t >> 2, c0 = (t & 3) * 8;
  for (int k0 = 0; k0 < D_DIM; k0 += 32) {
    // stage 128x32 bf16 tiles of A and B: 512 16B chunks each, 2 per thread
    async16(A + (size_t)(tileM + r0) * D_DIM + k0 + c0,        Al + t * 8);
    async16(A + (size_t)(tileM + r0 + 64) * D_DIM + k0 + c0,   Al + (t + 256) * 8);
    async16(B + (size_t)(tileN + r0) * D_DIM + k0 + c0,        Bl + t * 8);
    async16(B + (size_t)(tileN + r0 + 64) * D_DIM + k0 + c0,   Bl + (t + 256) * 8);
    __syncthreads();   // drains vmcnt for global_load_lds
    bf16x8 af[4], bfr[4];
#pragma unroll
    for (int mi = 0; mi < 4; ++mi)
      af[mi] = *(const bf16x8*)&Al[(waveM + mi * 16 + l16) * 32 + quad * 8];
#pragma unroll
    for (int ni = 0; ni < 4; ++ni)
      bfr[ni] = *(const bf16x8*)&Bl[(waveN + ni * 16 + l16) * 32 + quad * 8];
#pragma unroll
    for (int mi = 0; mi < 4; ++mi)
#pragma unroll
      for (int ni = 0; ni < 4; ++ni)
        acc[mi][ni] = __builtin_amdgcn_mfma_f32_16x16x32_bf16(af[mi], bfr[ni], acc[mi][ni], 0, 0, 0);
    __syncthreads();   // before next-iter LDS overwrite
  }
}

// ---------------- GEMM1: weights = tanh(x @ W1^T), bf16 out -----------------
__global__ __launch_bounds__(256) void gemm1_tanh(const u16* __restrict__ A,  // x_bf [16384,512]
                                                  const u16* __restrict__ B,  // W1_bf [512,512]
                                                  u16* __restrict__ C) {      // weights [16384,512]
  __shared__ __align__(16) u16 Al[128 * 32];
  __shared__ __align__(16) u16 Bl[128 * 32];
  const int t = threadIdx.x, lane = t & 63, wave = t >> 6;
  const int quad = lane >> 4, l16 = lane & 15;
  const int tileM = blockIdx.y * 128, tileN = blockIdx.x * 128;
  const int waveM = (wave >> 1) * 64, waveN = (wave & 1) * 64;
  f32x4 acc[4][4];
  const f32x4 z = {0.f, 0.f, 0.f, 0.f};
#pragma unroll
  for (int mi = 0; mi < 4; ++mi)
#pragma unroll
    for (int ni = 0; ni < 4; ++ni) acc[mi][ni] = z;
  gemm_core(A, B, tileM, tileN, Al, Bl, acc, waveM, waveN, quad, l16);
#pragma unroll
  for (int mi = 0; mi < 4; ++mi) {
    const int m0 = tileM + waveM + mi * 16 + quad * 4;
#pragma unroll
    for (int ni = 0; ni < 4; ++ni) {
      const int n = tileN + waveN + ni * 16 + l16;
#pragma unroll
      for (int r = 0; r < 4; ++r)
        C[(size_t)(m0 + r) * D_DIM + n] = f2bf(tanhf(acc[mi][ni][r]));
    }
  }
}

// ---------------- pass 1: rowsum[b,l] = sum_s exp(W2 @ weights_b^T) ---------
// No per-element stores — GEMM + exp + wave-reduce + atomics only.
__global__ __launch_bounds__(256) void gemm2_rowsum(const u16* __restrict__ A,    // W2_bf [8960,512]
                                                    const u16* __restrict__ Ball, // weights [16384,512]
                                                    float* __restrict__ rowsum) { // [4,8960]
  __shared__ __align__(16) u16 Al[128 * 32];
  __shared__ __align__(16) u16 Bl[128 * 32];
  const int b = blockIdx.z;
  const u16* B = Ball + (size_t)b * S_DIM * D_DIM;
  const int t = threadIdx.x, lane = t & 63, wave = t >> 6;
  const int quad = lane >> 4, l16 = lane & 15;
  const int tileM = blockIdx.y * 128, tileN = blockIdx.x * 128;
  const int waveM = (wave >> 1) * 64, waveN = (wave & 1) * 64;
  f32x4 acc[4][4];
  const f32x4 z = {0.f, 0.f, 0.f, 0.f};
#pragma unroll
  for (int mi = 0; mi < 4; ++mi)
#pragma unroll
    for (int ni = 0; ni < 4; ++ni) acc[mi][ni] = z;
  gemm_core(A, B, tileM, tileN, Al, Bl, acc, waveM, waveN, quad, l16);

#pragma unroll
  for (int mi = 0; mi < 4; ++mi) {
    const int l0 = tileM + waveM + mi * 16 + quad * 4;
    float rs[4] = {0.f, 0.f, 0.f, 0.f};
#pragma unroll
    for (int ni = 0; ni < 4; ++ni)
#pragma unroll
      for (int r = 0; r < 4; ++r)
        rs[r] += __expf(acc[mi][ni][r]);
#pragma unroll
    for (int r = 0; r < 4; ++r) {   // reduce over the 16 columns held by this quad-group
      float v = rs[r];
      v += __shfl_xor(v, 1);
      v += __shfl_xor(v, 2);
      v += __shfl_xor(v, 4);
      v += __shfl_xor(v, 8);
      if (l16 == 0) atomicAdd(&rowsum[(size_t)b * LPAD + l0 + r], v);
    }
  }
}

// ---------------- pass 2: att = exp(z)/rowsum (recomputed), + colsum --------
// Recomputes the identical GEMM (bit-identical acc => exactly consistent with
// pass-1 rowsum), writes f32 att directly, accumulates colsum in-register.
__global__ __launch_bounds__(256) void gemm2_att(const u16* __restrict__ A,      // W2_bf [8960,512]
                                                 const u16* __restrict__ Ball,   // weights [16384,512]
                                                 const float* __restrict__ rowsum,
                                                 float* __restrict__ att,        // [4,8921,4096]
                                                 float* __restrict__ colsum) {   // [4,4096]
  __shared__ __align__(16) u16 Al[128 * 32];
  __shared__ __align__(16) u16 Bl[128 * 32];
  const int b = blockIdx.z;
  const u16* B = Ball + (size_t)b * S_DIM * D_DIM;
  const int t = threadIdx.x, lane = t & 63, wave = t >> 6;
  const int quad = lane >> 4, l16 = lane & 15;
  const int tileM = blockIdx.y * 128, tileN = blockIdx.x * 128;
  const int waveM = (wave >> 1) * 64, waveN = (wave & 1) * 64;
  f32x4 acc[4][4];
  const f32x4 z = {0.f, 0.f, 0.f, 0.f};
#pragma unroll
  for (int mi = 0; mi < 4; ++mi)
#pragma unroll
    for (int ni = 0; ni < 4; ++ni) acc[mi][ni] = z;
  gemm_core(A, B, tileM, tileN, Al, Bl, acc, waveM, waveN, quad, l16);

  float cs[4] = {0.f, 0.f, 0.f, 0.f};   // colsum partial per ni (s = base + ni*16 + l16)
#pragma unroll
  for (int mi = 0; mi < 4; ++mi) {
    const int l0 = tileM + waveM + mi * 16 + quad * 4;
    float inv[4];
#pragma unroll
    for (int r = 0; r < 4; ++r) {
      const int l = l0 + r;
      inv[r] = (l < L_DIM) ? 1.0f / rowsum[(size_t)b * LPAD + l] : 0.0f;
    }
#pragma unroll
    for (int ni = 0; ni < 4; ++ni) {
      const int s = tileN + waveN + ni * 16 + l16;
#pragma unroll
      for (int r = 0; r < 4; ++r) {
        const float v = __expf(acc[mi][ni][r]) * inv[r];
        cs[ni] += v;
        const int l = l0 + r;
        if (l < L_DIM)
          att[((size_t)b * L_DIM + l) * S_DIM + s] = v;
      }
    }
  }
  // cross-quad reduce (same s lives in all 4 quads), then one atomic per s
#pragma unroll
  for (int ni = 0; ni < 4; ++ni) {
    float v = cs[ni];
    v += __shfl_xor(v, 16);
    v += __shfl_xor(v, 32);
    if (quad == 0) {
      const int s = tileN + waveN + ni * 16 + l16;
      atomicAdd(&colsum[(size_t)b * S_DIM + s], v);
    }
  }
}

// ---------------- out[b,d] = sum_s colsum[b,s]*x[b,s,d] / R -----------------
__global__ __launch_bounds__(256) void out_kernel(const float* __restrict__ x,
                                                  const float* __restrict__ colsum,
                                                  float* __restrict__ out) {
  const int b = blockIdx.y, s0 = blockIdx.x * 64, t = threadIdx.x;
  float a0 = 0.f, a1 = 0.f;
  for (int i = 0; i < 64; ++i) {
    const int s = s0 + i;
    const float c = colsum[(size_t)b * S_DIM + s];
    const float* xr = x + ((size_t)b * S_DIM + s) * D_DIM;
    a0 += c * xr[t];
    a1 += c * xr[t + 256];
  }
  const float invR = 1.0f / 8921.0f;
  atomicAdd(out + b * D_DIM + t,       a0 * invR);
  atomicAdd(out + b * D_DIM + t + 256, a1 * invR);
}

extern "C" void kernel_launch(void* const* d_in, const int* in_sizes, int n_in,
                              void* d_out, int out_size, void* d_ws, size_t ws_size,
                              hipStream_t stream) {
  const float* x  = (const float*)d_in[0];   // [4,4096,512]
  const float* W1 = (const float*)d_in[1];   // [512,512]
  const float* W2 = (const float*)d_in[2];   // [8921,512]
  float* out = (float*)d_out;                // 2048 + 4*8921*4096
  float* att = out + 2048;

  char* ws = (char*)d_ws;
  u16*   x_bf   = (u16*)(ws + 0);            // 16,777,216 B
  u16*   wt_bf  = (u16*)(ws + 16777216);     // 16,777,216 B
  u16*   w1_bf  = (u16*)(ws + 33554432);     //    524,288 B
  u16*   w2_bf  = (u16*)(ws + 34078720);     //  9,175,040 B
  float* rowsum = (float*)(ws + 43253760);   //    143,360 B
  float* colsum = (float*)(ws + 43397120);   //     65,536 B
  // total ws need: 43,462,656 B — no scores bounce buffer anymore

  // rowsum and colsum are adjacent: one memset covers both
  hipMemsetAsync(rowsum, 0, (size_t)B_DIM * LPAD * 4 + (size_t)B_DIM * S_DIM * 4, stream);
  hipMemsetAsync(out, 0, 2048 * sizeof(float), stream);

  cast_pad_kernel<<<8192, 256, 0, stream>>>(x,  x_bf,  8388608LL, 8388608LL);
  cast_pad_kernel<<<256,  256, 0, stream>>>(W1, w1_bf, 262144LL,  262144LL);
  cast_pad_kernel<<<4480, 256, 0, stream>>>(W2, w2_bf, (long long)L_DIM * 512, (long long)LPAD * 512);

  gemm1_tanh<<<dim3(4, 128), 256, 0, stream>>>(x_bf, w1_bf, wt_bf);

  const dim3 g2(S_DIM / 128, LPAD / 128, B_DIM);   // (32, 70, 4)
  gemm2_rowsum<<<g2, 256, 0, stream>>>(w2_bf, wt_bf, rowsum);
  gemm2_att  <<<g2, 256, 0, stream>>>(w2_bf, wt_bf, rowsum, att, colsum);

  out_kernel<<<dim3(64, 4), 256, 0, stream>>>(x, colsum, out);
}

// Round 3
// 987.041 us; speedup vs baseline: 1.0647x; 1.0046x over previous
//
#include <hip/hip_runtime.h>
#include <stdint.h>

typedef unsigned short u16;
typedef __bf16 bf16x8 __attribute__((ext_vector_type(8)));
typedef float f32x4 __attribute__((ext_vector_type(4)));

#define S_DIM 4096
#define D_DIM 512
#define B_DIM 4
#define L_DIM 8921
#define LPAD  8960   // L padded to multiple of 128
#define M1    16384  // B*S

__device__ __forceinline__ u16 f2bf(float f) {
  uint32_t u = __float_as_uint(f);
  u += 0x7FFFu + ((u >> 16) & 1u);   // RNE
  return (u16)(u >> 16);
}
__device__ __forceinline__ void async16(const u16* g, u16* l) {
  __builtin_amdgcn_global_load_lds((const __attribute__((address_space(1))) void*)g,
                                   (__attribute__((address_space(3))) void*)l, 16, 0, 0);
}

// ---------------- cast f32 -> bf16 with optional zero tail padding ----------
__global__ __launch_bounds__(256) void cast_pad_kernel(const float* __restrict__ src,
                                                       u16* __restrict__ dst,
                                                       long long nsrc, long long ndst) {
  long long i = ((long long)blockIdx.x * 256 + threadIdx.x) * 4;
  if (i >= ndst) return;
  ushort4 o;
  if (i < nsrc) {
    float4 v = *(const float4*)(src + i);
    o.x = f2bf(v.x); o.y = f2bf(v.y); o.z = f2bf(v.z); o.w = f2bf(v.w);
  } else {
    o.x = 0; o.y = 0; o.z = 0; o.w = 0;
  }
  *(ushort4*)(dst + i) = o;
}

// ---------------- shared 128x128xK NT GEMM core (m97 structure) -------------
// C[tileM+128][tileN+128] += A[M,K] * B[N,K]^T, K=512, bf16, f32 acc.
__device__ __forceinline__ void gemm_core(const u16* __restrict__ A, const u16* __restrict__ B,
                                          int tileM, int tileN, u16* Al, u16* Bl,
                                          f32x4 acc[4][4], int waveM, int waveN,
                                          int quad, int l16) {
  const int t = threadIdx.x;
  const int r0 = t >> 2, c0 = (t & 3) * 8;
  for (int k0 = 0; k0 < D_DIM; k0 += 32) {
    // stage 128x32 bf16 tiles of A and B: 512 16B chunks each, 2 per thread
    async16(A + (size_t)(tileM + r0) * D_DIM + k0 + c0,        Al + t * 8);
    async16(A + (size_t)(tileM + r0 + 64) * D_DIM + k0 + c0,   Al + (t + 256) * 8);
    async16(B + (size_t)(tileN + r0) * D_DIM + k0 + c0,        Bl + t * 8);
    async16(B + (size_t)(tileN + r0 + 64) * D_DIM + k0 + c0,   Bl + (t + 256) * 8);
    __syncthreads();   // drains vmcnt for global_load_lds
    bf16x8 af[4], bfr[4];
#pragma unroll
    for (int mi = 0; mi < 4; ++mi)
      af[mi] = *(const bf16x8*)&Al[(waveM + mi * 16 + l16) * 32 + quad * 8];
#pragma unroll
    for (int ni = 0; ni < 4; ++ni)
      bfr[ni] = *(const bf16x8*)&Bl[(waveN + ni * 16 + l16) * 32 + quad * 8];
#pragma unroll
    for (int mi = 0; mi < 4; ++mi)
#pragma unroll
      for (int ni = 0; ni < 4; ++ni)
        acc[mi][ni] = __builtin_amdgcn_mfma_f32_16x16x32_bf16(af[mi], bfr[ni], acc[mi][ni], 0, 0, 0);
    __syncthreads();   // before next-iter LDS overwrite
  }
}

// XCD stripe swizzle for the gemm2 grid (32 x-tiles, 70 y-tiles, 2240 blocks
// per z-slice, 2240 % 8 == 0 so round-robin XCD assignment is phase-aligned).
// Each XCD owns a 4-wide s-stripe: its 4 B-panels (512 KB) stay L2-resident
// across all 70 l-tiles; A-panels are consumed by 4 consecutive same-XCD blocks.
// Bijective: (x,y) <-> j. Output mapping per block unchanged => bit-identical.
__device__ __forceinline__ void swizzle_xy(int bx, int by, int& tx, int& ty) {
  const int j = by * (S_DIM / 128) + bx;   // 0..2239
  const int xcd = j & 7;
  const int n = j >> 3;                    // 0..279
  tx = xcd * 4 + (n & 3);                  // 0..31
  ty = n >> 2;                             // 0..69
}

// ---------------- GEMM1: weights = tanh(x @ W1^T), bf16 out -----------------
__global__ __launch_bounds__(256) void gemm1_tanh(const u16* __restrict__ A,  // x_bf [16384,512]
                                                  const u16* __restrict__ B,  // W1_bf [512,512]
                                                  u16* __restrict__ C) {      // weights [16384,512]
  __shared__ __align__(16) u16 Al[128 * 32];
  __shared__ __align__(16) u16 Bl[128 * 32];
  const int t = threadIdx.x, lane = t & 63, wave = t >> 6;
  const int quad = lane >> 4, l16 = lane & 15;
  const int tileM = blockIdx.y * 128, tileN = blockIdx.x * 128;
  const int waveM = (wave >> 1) * 64, waveN = (wave & 1) * 64;
  f32x4 acc[4][4];
  const f32x4 z = {0.f, 0.f, 0.f, 0.f};
#pragma unroll
  for (int mi = 0; mi < 4; ++mi)
#pragma unroll
    for (int ni = 0; ni < 4; ++ni) acc[mi][ni] = z;
  gemm_core(A, B, tileM, tileN, Al, Bl, acc, waveM, waveN, quad, l16);
#pragma unroll
  for (int mi = 0; mi < 4; ++mi) {
    const int m0 = tileM + waveM + mi * 16 + quad * 4;
#pragma unroll
    for (int ni = 0; ni < 4; ++ni) {
      const int n = tileN + waveN + ni * 16 + l16;
#pragma unroll
      for (int r = 0; r < 4; ++r)
        C[(size_t)(m0 + r) * D_DIM + n] = f2bf(tanhf(acc[mi][ni][r]));
    }
  }
}

// ---------------- pass 1: rowsum[b,l] = sum_s exp(W2 @ weights_b^T) ---------
__global__ __launch_bounds__(256) void gemm2_rowsum(const u16* __restrict__ A,    // W2_bf [8960,512]
                                                    const u16* __restrict__ Ball, // weights [16384,512]
                                                    float* __restrict__ rowsum) { // [4,8960]
  __shared__ __align__(16) u16 Al[128 * 32];
  __shared__ __align__(16) u16 Bl[128 * 32];
  const int b = blockIdx.z;
  const u16* B = Ball + (size_t)b * S_DIM * D_DIM;
  const int t = threadIdx.x, lane = t & 63, wave = t >> 6;
  const int quad = lane >> 4, l16 = lane & 15;
  int tx, ty;
  swizzle_xy(blockIdx.x, blockIdx.y, tx, ty);
  const int tileM = ty * 128, tileN = tx * 128;
  const int waveM = (wave >> 1) * 64, waveN = (wave & 1) * 64;
  f32x4 acc[4][4];
  const f32x4 z = {0.f, 0.f, 0.f, 0.f};
#pragma unroll
  for (int mi = 0; mi < 4; ++mi)
#pragma unroll
    for (int ni = 0; ni < 4; ++ni) acc[mi][ni] = z;
  gemm_core(A, B, tileM, tileN, Al, Bl, acc, waveM, waveN, quad, l16);

#pragma unroll
  for (int mi = 0; mi < 4; ++mi) {
    const int l0 = tileM + waveM + mi * 16 + quad * 4;
    float rs[4] = {0.f, 0.f, 0.f, 0.f};
#pragma unroll
    for (int ni = 0; ni < 4; ++ni)
#pragma unroll
      for (int r = 0; r < 4; ++r)
        rs[r] += __expf(acc[mi][ni][r]);
#pragma unroll
    for (int r = 0; r < 4; ++r) {   // reduce over the 16 columns held by this quad-group
      float v = rs[r];
      v += __shfl_xor(v, 1);
      v += __shfl_xor(v, 2);
      v += __shfl_xor(v, 4);
      v += __shfl_xor(v, 8);
      if (l16 == 0) atomicAdd(&rowsum[(size_t)b * LPAD + l0 + r], v);
    }
  }
}

// ---------------- pass 2: att = exp(z)/rowsum (recomputed), + colsum --------
// Recomputes the identical GEMM (bit-identical acc => exactly consistent with
// pass-1 rowsum), writes f32 att directly, accumulates colsum in-register.
__global__ __launch_bounds__(256) void gemm2_att(const u16* __restrict__ A,      // W2_bf [8960,512]
                                                 const u16* __restrict__ Ball,   // weights [16384,512]
                                                 const float* __restrict__ rowsum,
                                                 float* __restrict__ att,        // [4,8921,4096]
                                                 float* __restrict__ colsum) {   // [4,4096]
  __shared__ __align__(16) u16 Al[128 * 32];
  __shared__ __align__(16) u16 Bl[128 * 32];
  const int b = blockIdx.z;
  const u16* B = Ball + (size_t)b * S_DIM * D_DIM;
  const int t = threadIdx.x, lane = t & 63, wave = t >> 6;
  const int quad = lane >> 4, l16 = lane & 15;
  int tx, ty;
  swizzle_xy(blockIdx.x, blockIdx.y, tx, ty);
  const int tileM = ty * 128, tileN = tx * 128;
  const int waveM = (wave >> 1) * 64, waveN = (wave & 1) * 64;
  f32x4 acc[4][4];
  const f32x4 z = {0.f, 0.f, 0.f, 0.f};
#pragma unroll
  for (int mi = 0; mi < 4; ++mi)
#pragma unroll
    for (int ni = 0; ni < 4; ++ni) acc[mi][ni] = z;
  gemm_core(A, B, tileM, tileN, Al, Bl, acc, waveM, waveN, quad, l16);

  float cs[4] = {0.f, 0.f, 0.f, 0.f};   // colsum partial per ni (s = base + ni*16 + l16)
#pragma unroll
  for (int mi = 0; mi < 4; ++mi) {
    const int l0 = tileM + waveM + mi * 16 + quad * 4;
    float inv[4];
#pragma unroll
    for (int r = 0; r < 4; ++r) {
      const int l = l0 + r;
      inv[r] = (l < L_DIM) ? 1.0f / rowsum[(size_t)b * LPAD + l] : 0.0f;
    }
#pragma unroll
    for (int ni = 0; ni < 4; ++ni) {
      const int s = tileN + waveN + ni * 16 + l16;
#pragma unroll
      for (int r = 0; r < 4; ++r) {
        const float v = __expf(acc[mi][ni][r]) * inv[r];
        cs[ni] += v;
        const int l = l0 + r;
        if (l < L_DIM)
          att[((size_t)b * L_DIM + l) * S_DIM + s] = v;
      }
    }
  }
  // cross-quad reduce (same s lives in all 4 quads), then one atomic per s
#pragma unroll
  for (int ni = 0; ni < 4; ++ni) {
    float v = cs[ni];
    v += __shfl_xor(v, 16);
    v += __shfl_xor(v, 32);
    if (quad == 0) {
      const int s = tileN + waveN + ni * 16 + l16;
      atomicAdd(&colsum[(size_t)b * S_DIM + s], v);
    }
  }
}

// ---------------- out[b,d] = sum_s colsum[b,s]*x[b,s,d] / R -----------------
__global__ __launch_bounds__(256) void out_kernel(const float* __restrict__ x,
                                                  const float* __restrict__ colsum,
                                                  float* __restrict__ out) {
  const int b = blockIdx.y, s0 = blockIdx.x * 64, t = threadIdx.x;
  float a0 = 0.f, a1 = 0.f;
  for (int i = 0; i < 64; ++i) {
    const int s = s0 + i;
    const float c = colsum[(size_t)b * S_DIM + s];
    const float* xr = x + ((size_t)b * S_DIM + s) * D_DIM;
    a0 += c * xr[t];
    a1 += c * xr[t + 256];
  }
  const float invR = 1.0f / 8921.0f;
  atomicAdd(out + b * D_DIM + t,       a0 * invR);
  atomicAdd(out + b * D_DIM + t + 256, a1 * invR);
}

extern "C" void kernel_launch(void* const* d_in, const int* in_sizes, int n_in,
                              void* d_out, int out_size, void* d_ws, size_t ws_size,
                              hipStream_t stream) {
  const float* x  = (const float*)d_in[0];   // [4,4096,512]
  const float* W1 = (const float*)d_in[1];   // [512,512]
  const float* W2 = (const float*)d_in[2];   // [8921,512]
  float* out = (float*)d_out;                // 2048 + 4*8921*4096
  float* att = out + 2048;

  char* ws = (char*)d_ws;
  u16*   x_bf   = (u16*)(ws + 0);            // 16,777,216 B
  u16*   wt_bf  = (u16*)(ws + 16777216);     // 16,777,216 B
  u16*   w1_bf  = (u16*)(ws + 33554432);     //    524,288 B
  u16*   w2_bf  = (u16*)(ws + 34078720);     //  9,175,040 B
  float* rowsum = (float*)(ws + 43253760);   //    143,360 B
  float* colsum = (float*)(ws + 43397120);   //     65,536 B
  // total ws need: 43,462,656 B

  // rowsum and colsum are adjacent: one memset covers both
  hipMemsetAsync(rowsum, 0, (size_t)B_DIM * LPAD * 4 + (size_t)B_DIM * S_DIM * 4, stream);
  hipMemsetAsync(out, 0, 2048 * sizeof(float), stream);

  cast_pad_kernel<<<8192, 256, 0, stream>>>(x,  x_bf,  8388608LL, 8388608LL);
  cast_pad_kernel<<<256,  256, 0, stream>>>(W1, w1_bf, 262144LL,  262144LL);
  cast_pad_kernel<<<4480, 256, 0, stream>>>(W2, w2_bf, (long long)L_DIM * 512, (long long)LPAD * 512);

  gemm1_tanh<<<dim3(4, 128), 256, 0, stream>>>(x_bf, w1_bf, wt_bf);

  const dim3 g2(S_DIM / 128, LPAD / 128, B_DIM);   // (32, 70, 4)
  gemm2_rowsum<<<g2, 256, 0, stream>>>(w2_bf, wt_bf, rowsum);
  gemm2_att  <<<g2, 256, 0, stream>>>(w2_bf, wt_bf, rowsum, att, colsum);

  out_kernel<<<dim3(64, 4), 256, 0, stream>>>(x, colsum, out);
}